// Round 1
// baseline (78.428 us; speedup 1.0000x reference)
//
#include <hip/hip_runtime.h>
#include <math.h>

// Sobel: img [32,1,1024,1024] f32, G [2,1,3,3] f32 (fixed taps, hardcoded).
// out [32,1,1024,1024] f32 = sqrt(gx^2+gy^2), 1-pixel border zeroed.
//
// Gx = [[2,0,-2],[4,0,-4],[2,0,-2]]  = [1,2,1]^T (vert) x [2,0,-2] (horiz)
// Gy = [[2,4,2],[0,0,0],[-2,-4,-2]]  = [1,0,-1]^T (vert) x [2,4,2] (horiz)
//
// One block (256 threads) per output row; each thread computes 4 pixels
// (float4). Rows y-1,y,y+1 are read; adjacent blocks hit L2 on re-reads.

#define SOBEL_W 1024
#define SOBEL_H 1024

__global__ __launch_bounds__(256) void Sobel_34763465294602_kernel(
    const float* __restrict__ img, float* __restrict__ out) {
    const int row_id = blockIdx.x;             // b*H + y
    const int y = row_id & (SOBEL_H - 1);
    const int x0 = threadIdx.x << 2;           // 0,4,...,1020

    float* orow = out + (size_t)row_id * SOBEL_W;

    if (y == 0 || y == SOBEL_H - 1) {
        *reinterpret_cast<float4*>(orow + x0) = make_float4(0.f, 0.f, 0.f, 0.f);
        return;
    }

    const float* r0 = img + (size_t)(row_id - 1) * SOBEL_W;  // y-1
    const float* r1 = r0 + SOBEL_W;                          // y
    const float* r2 = r1 + SOBEL_W;                          // y+1

    // columns x0-1 .. x0+4  (6 values per row)
    float a[6], b[6], c[6];
    const float4 va = *reinterpret_cast<const float4*>(r0 + x0);
    const float4 vb = *reinterpret_cast<const float4*>(r1 + x0);
    const float4 vc = *reinterpret_cast<const float4*>(r2 + x0);
    a[1] = va.x; a[2] = va.y; a[3] = va.z; a[4] = va.w;
    b[1] = vb.x; b[2] = vb.y; b[3] = vb.z; b[4] = vb.w;
    c[1] = vc.x; c[2] = vc.y; c[3] = vc.z; c[4] = vc.w;
    const bool has_l = (x0 > 0);
    const bool has_r = (x0 + 4 < SOBEL_W);
    a[0] = has_l ? r0[x0 - 1] : 0.f;  a[5] = has_r ? r0[x0 + 4] : 0.f;
    b[0] = has_l ? r1[x0 - 1] : 0.f;  b[5] = has_r ? r1[x0 + 4] : 0.f;
    c[0] = has_l ? r2[x0 - 1] : 0.f;  c[5] = has_r ? r2[x0 + 4] : 0.f;

    // separable partial sums per column
    float t[6], s[6];
#pragma unroll
    for (int i = 0; i < 6; ++i) {
        t[i] = a[i] + 2.f * b[i] + c[i];   // vertical [1,2,1]
        s[i] = a[i] - c[i];                // vertical [1,0,-1]
    }

    float m[4];
#pragma unroll
    for (int j = 0; j < 4; ++j) {
        const int i = j + 1;
        const float gx = 2.f * (t[i - 1] - t[i + 1]);            // horiz [2,0,-2]
        const float gy = 2.f * s[i - 1] + 4.f * s[i] + 2.f * s[i + 1];  // horiz [2,4,2]
        m[j] = sqrtf(gx * gx + gy * gy);
    }
    const int col0 = x0;
    if (col0 == 0) m[0] = 0.f;                       // x == 0
    if (col0 + 3 == SOBEL_W - 1) m[3] = 0.f;         // x == W-1

    *reinterpret_cast<float4*>(orow + x0) = make_float4(m[0], m[1], m[2], m[3]);
}

extern "C" void kernel_launch(void* const* d_in, const int* in_sizes, int n_in,
                              void* d_out, int out_size, void* d_ws, size_t ws_size,
                              hipStream_t stream) {
    const float* img = (const float*)d_in[0];
    // d_in[1] = G (fixed Sobel taps) — hardcoded in the kernel.
    float* out = (float*)d_out;

    const int n_rows = out_size / SOBEL_W;   // 32 * 1024 = 32768
    Sobel_34763465294602_kernel<<<n_rows, 256, 0, stream>>>(img, out);
}

// Round 2
// 47.988 us; speedup vs baseline: 1.6343x; 1.6343x over previous
//
#include <hip/hip_runtime.h>
#include <math.h>

// Sobel: img [32,1,1024,1024] f32 -> out [32,1,1024,1024] f32
//   mag = sqrt(Gx^2 + Gy^2), 1-px border zeroed. Taps hardcoded (fixed input).
//   Gx = [1,2,1]^T x [2,0,-2],  Gy = [1,0,-1]^T x [2,4,2]  (separable)
//
// R1: 16-row tile per block with register-rotating 3-row window.
//   - reads 18 rows per 16 output rows -> <=1.125x HBM fetch (was 1.46x)
//   - XCD-aware swizzle: vertically adjacent tiles share an XCD L2,
//     absorbing the inter-tile halo re-read
//   - 16x unrolled row loop gives deep load-ahead ILP per thread

#define SOBEL_W 1024
#define SOBEL_H 1024
#define RPB 16
#define TILES_PER_IMG (SOBEL_H / RPB)   // 64

__global__ __launch_bounds__(256) void Sobel_34763465294602_kernel(
    const float* __restrict__ img, float* __restrict__ out) {
    // XCD-aware swizzle (gridDim.x = 2048, divisible by 8): consecutive
    // tiles (adjacent in y) land on the same XCD.
    const int cpx = gridDim.x >> 3;
    const int bid = blockIdx.x;
    const int tile = (bid & 7) * cpx + (bid >> 3);

    const int b  = tile / TILES_PER_IMG;
    const int y0 = (tile - b * TILES_PER_IMG) * RPB;
    const int x0 = threadIdx.x << 2;

    const float* ibase = img + (size_t)b * SOBEL_H * SOBEL_W;
    float* obase = out + (size_t)b * SOBEL_H * SOBEL_W;

    const bool has_l = (x0 > 0);
    const bool has_r = (x0 + 4 < SOBEL_W);

    // 3-row rotating window; 6 columns each (x0-1 .. x0+4)
    float A[6], B[6], C[6];

    auto load_row = [&](int y, float (&dst)[6]) {
        const float* r = ibase + (size_t)y * SOBEL_W;
        const float4 v = *reinterpret_cast<const float4*>(r + x0);
        dst[1] = v.x; dst[2] = v.y; dst[3] = v.z; dst[4] = v.w;
        dst[0] = has_l ? r[x0 - 1] : 0.f;
        dst[5] = has_r ? r[x0 + 4] : 0.f;
    };

    load_row(max(y0 - 1, 0), A);   // clamped: value unused when y==0
    load_row(y0, B);

#pragma unroll
    for (int rr = 0; rr < RPB; ++rr) {
        const int y = y0 + rr;
        load_row(min(y + 1, SOBEL_H - 1), C);  // clamped: unused when y==H-1
        float* orow = obase + (size_t)y * SOBEL_W;

        if (y == 0 || y == SOBEL_H - 1) {
            *reinterpret_cast<float4*>(orow + x0) = make_float4(0.f, 0.f, 0.f, 0.f);
        } else {
            float t[6], s[6];
#pragma unroll
            for (int i = 0; i < 6; ++i) {
                t[i] = A[i] + 2.f * B[i] + C[i];   // vertical [1,2,1]
                s[i] = A[i] - C[i];                // vertical [1,0,-1]
            }
            float m[4];
#pragma unroll
            for (int j = 0; j < 4; ++j) {
                const float gx = 2.f * (t[j] - t[j + 2]);                  // [2,0,-2]
                const float gy = 2.f * s[j] + 4.f * s[j + 1] + 2.f * s[j + 2];  // [2,4,2]
                m[j] = sqrtf(gx * gx + gy * gy);
            }
            if (x0 == 0) m[0] = 0.f;
            if (x0 + 4 == SOBEL_W) m[3] = 0.f;
            *reinterpret_cast<float4*>(orow + x0) = make_float4(m[0], m[1], m[2], m[3]);
        }

        // rotate window
#pragma unroll
        for (int i = 0; i < 6; ++i) { A[i] = B[i]; B[i] = C[i]; }
    }
}

extern "C" void kernel_launch(void* const* d_in, const int* in_sizes, int n_in,
                              void* d_out, int out_size, void* d_ws, size_t ws_size,
                              hipStream_t stream) {
    const float* img = (const float*)d_in[0];
    // d_in[1] = G (fixed Sobel taps) — hardcoded in the kernel.
    float* out = (float*)d_out;

    const int n_tiles = (out_size / SOBEL_W) / RPB;   // 32 * 64 = 2048
    Sobel_34763465294602_kernel<<<n_tiles, 256, 0, stream>>>(img, out);
}